// Round 7
// baseline (186.665 us; speedup 1.0000x reference)
//
#include <hip/hip_runtime.h>

// SlidingWindowAttention: B=1, S=4096, D=1024, H=16, d=64, WIN=512 (256 back / 255 fwd)
// Inputs/outputs FP32 storage (values bf16-rounded by harness).
//
// Pipeline:
//   0) cvt_f32_bf16 x3 : x, Wqkv, Wout -> bf16 (ws)
//   1) gemm_qkv        : 128x128 tile, BK=64 (32 MFMA/wave/barrier-round),
//                        scatters Q->Qb, K->Kp(pad), V->Vb
//   2) repack_v        : Vb -> VTp padded (h,d,key+256); zeroes Kp/VTp pads
//   3) swa_fused       : 128 queries/block, 4 waves (32 q/wave), 10 key
//                        tiles, gll16 staging, fixed-max softmax -> o
//   4) gemm_out        : 64x128 tile, BK=64 -> fp32 out
//
// LDS swizzle (all kernels): row of 64 bf16 = 8 chunks of 8; chunk c of row r
// lives in slot c ^ (r & 7). Row stride 128 B == 0 mod 32 banks, so bank
// depends only on slot -> gll16 DMA writes and b128 fragment reads are
// conflict-free.

typedef __bf16 bf16x8 __attribute__((ext_vector_type(8)));
typedef float f32x4 __attribute__((ext_vector_type(4)));
typedef unsigned short u16;
typedef unsigned int u32;

#define MFMA16(a, b, c) __builtin_amdgcn_mfma_f32_16x16x32_bf16(a, b, c, 0, 0, 0)

__device__ __forceinline__ u16 f2b(float f) {   // RNE f32 -> bf16 bits
  union { float f; u32 u; } x; x.f = f;
  u32 r = x.u + 0x7fffu + ((x.u >> 16) & 1u);
  return (u16)(r >> 16);
}

union U8x16 { int4 v; u16 u[8]; };

// async 16B global -> LDS (dest = wave-uniform base + lane*16, HW-generated)
__device__ __forceinline__ void gll16(const u16* g, u16* l) {
  __builtin_amdgcn_global_load_lds(
      (const __attribute__((address_space(1))) u16*)g,
      (__attribute__((address_space(3))) u16*)l, 16, 0, 0);
}

// ---------------------------------------------------------------------------
__global__ void cvt_f32_bf16(const float* __restrict__ in, u16* __restrict__ out, int n8)
{
  const int i = blockIdx.x * blockDim.x + threadIdx.x;
  if (i >= n8) return;
  const float4 a = ((const float4*)in)[i * 2];
  const float4 b = ((const float4*)in)[i * 2 + 1];
  U8x16 t;
  t.u[0] = f2b(a.x); t.u[1] = f2b(a.y); t.u[2] = f2b(a.z); t.u[3] = f2b(a.w);
  t.u[4] = f2b(b.x); t.u[5] = f2b(b.y); t.u[6] = f2b(b.z); t.u[7] = f2b(b.w);
  ((int4*)out)[i] = t.v;
}

// ---------------------------------------------------------------------------
// QKV GEMM: 128x128 tile, BK=64, grid (24, 32) = 768 blocks = 3/CU.
// 2x2 waves, each 64x64 output: 4x4 MFMA tiles x 2 K-halves = 32 MFMA/round.
// Staging per wave per round: 4 gll16 (A) + 4 gll16 (B). 16 rounds.
// Epilogue scatters: Q (n<1024) -> Qb; K -> Kp (h, key+256, d); V -> Vb.
// ---------------------------------------------------------------------------
__global__ __launch_bounds__(256, 3) void gemm_qkv(
    const u16* __restrict__ A, const u16* __restrict__ B,
    const float* __restrict__ bias,
    u16* __restrict__ Qb, u16* __restrict__ Kp, u16* __restrict__ Vb)
{
  __shared__ u16 As[128 * 64];   // 16 KB
  __shared__ u16 Bs[128 * 64];   // 16 KB

  const int K = 1024;
  const int tid  = threadIdx.x;
  const int lane = tid & 63;
  const int wave = tid >> 6;
  const int quad = lane >> 4;
  const int c16  = lane & 15;
  const int wr   = wave >> 1;            // M half (64 rows)
  const int wc   = wave & 1;             // N half (64 cols)
  const long m0 = (long)blockIdx.y * 128;
  const long n0 = (long)blockIdx.x * 128;

  // staging: wave stages rows [wave*32, +32) of each matrix; lane i covers
  // row grp+(i>>3), slot i&7, global chunk (i&7)^((i>>3)&7)
  const int rowo   = lane >> 3;
  const int schunk = (lane & 7) ^ rowo;
  const u16* gA[4]; const u16* gB[4];
  u16* lA[4]; u16* lB[4];
#pragma unroll
  for (int i = 0; i < 4; ++i) {
    gA[i] = &A[(m0 + wave * 32 + i * 8 + rowo) * K + schunk * 8];
    gB[i] = &B[(n0 + wave * 32 + i * 8 + rowo) * K + schunk * 8];
    lA[i] = &As[(wave * 32 + i * 8) * 64];
    lB[i] = &Bs[(wave * 32 + i * 8) * 64];
  }

  const int rsw  = c16 & 7;
  const int off0 = (quad ^ rsw) * 8;
  const int off1 = ((4 + quad) ^ rsw) * 8;
  const u16* rA[4]; const u16* rB[4];
#pragma unroll
  for (int i = 0; i < 4; ++i) {
    rA[i] = &As[(wr * 64 + i * 16 + c16) * 64];
    rB[i] = &Bs[(wc * 64 + i * 16 + c16) * 64];
  }

  f32x4 acc[4][4];
#pragma unroll
  for (int i = 0; i < 4; ++i)
#pragma unroll
    for (int j = 0; j < 4; ++j)
      acc[i][j] = f32x4{0.f, 0.f, 0.f, 0.f};

  for (int k0 = 0; k0 < K; k0 += 64) {
    __syncthreads();
#pragma unroll
    for (int i = 0; i < 4; ++i) { gll16(gA[i], lA[i]); gA[i] += 64; }
#pragma unroll
    for (int i = 0; i < 4; ++i) { gll16(gB[i], lB[i]); gB[i] += 64; }
    __syncthreads();

#pragma unroll
    for (int h = 0; h < 2; ++h) {
      const int off = h ? off1 : off0;
      bf16x8 af[4], bfr[4];
#pragma unroll
      for (int i = 0; i < 4; ++i) af[i]  = *(const bf16x8*)(rA[i] + off);
#pragma unroll
      for (int j = 0; j < 4; ++j) bfr[j] = *(const bf16x8*)(rB[j] + off);
#pragma unroll
      for (int i = 0; i < 4; ++i)
#pragma unroll
        for (int j = 0; j < 4; ++j)
          acc[i][j] = MFMA16(af[i], bfr[j], acc[i][j]);
    }
  }

  const int region = (int)(n0 >> 10);      // 0=Q, 1=K, 2=V (block-uniform)
#pragma unroll
  for (int i = 0; i < 4; ++i) {
    const long row0 = m0 + wr * 64 + i * 16 + quad * 4;
#pragma unroll
    for (int j = 0; j < 4; ++j) {
      const long col = n0 + wc * 64 + j * 16 + c16;
      const float bv = bias[col];
#pragma unroll
      for (int r = 0; r < 4; ++r) {
        const u16 v = f2b(acc[i][j][r] + bv);
        const long row = row0 + r;
        if (region == 0) {
          Qb[row * 1024 + col] = v;
        } else if (region == 1) {
          const int n1 = (int)(col - 1024);
          const int h = n1 >> 6, d = n1 & 63;
          Kp[((long)h * 4608 + row + 256) * 64 + d] = v;
        } else {
          Vb[row * 1024 + (col - 2048)] = v;
        }
      }
    }
  }
}

// ---------------------------------------------------------------------------
// Output GEMM: 64x128 tile, BK=64, grid (8, 64) = 512 blocks. 2x2 waves,
// each 32x64: 2x4 MFMA tiles x 2 K-halves = 16 MFMA/round. fp32 out.
// ---------------------------------------------------------------------------
__global__ __launch_bounds__(256, 4) void gemm_out(
    const u16* __restrict__ A, const u16* __restrict__ B,
    const float* __restrict__ bias, float* __restrict__ C)
{
  __shared__ u16 As[64 * 64];    // 8 KB
  __shared__ u16 Bs[128 * 64];   // 16 KB

  const int K = 1024, N = 1024;
  const int tid  = threadIdx.x;
  const int lane = tid & 63;
  const int wave = tid >> 6;
  const int quad = lane >> 4;
  const int c16  = lane & 15;
  const int wr   = wave >> 1;            // M half (32 rows)
  const int wc   = wave & 1;             // N half (64 cols)
  const long m0 = (long)blockIdx.y * 64;
  const long n0 = (long)blockIdx.x * 128;

  const int rowo   = lane >> 3;
  const int schunk = (lane & 7) ^ rowo;
  const u16* gA0 = &A[(m0 + wave * 16 + rowo) * K + schunk * 8];
  const u16* gA1 = gA0 + 8 * K;
  const u16* gB0 = &B[(n0 + wave * 32 + rowo) * K + schunk * 8];
  const u16* gB1 = gB0 + 8 * K;
  const u16* gB2 = gB0 + 16 * K;
  const u16* gB3 = gB0 + 24 * K;
  u16* const lA0 = &As[(wave * 16) * 64];
  u16* const lA1 = lA0 + 8 * 64;
  u16* const lB0 = &Bs[(wave * 32) * 64];
  u16* const lB1 = lB0 + 8 * 64;
  u16* const lB2 = lB0 + 16 * 64;
  u16* const lB3 = lB0 + 24 * 64;

  const int rsw  = c16 & 7;
  const int off0 = (quad ^ rsw) * 8;
  const int off1 = ((4 + quad) ^ rsw) * 8;
  const u16* rA[2]; const u16* rB[4];
#pragma unroll
  for (int i = 0; i < 2; ++i) rA[i] = &As[(wr * 32 + i * 16 + c16) * 64];
#pragma unroll
  for (int j = 0; j < 4; ++j) rB[j] = &Bs[(wc * 64 + j * 16 + c16) * 64];

  f32x4 acc[2][4];
#pragma unroll
  for (int i = 0; i < 2; ++i)
#pragma unroll
    for (int j = 0; j < 4; ++j)
      acc[i][j] = f32x4{0.f, 0.f, 0.f, 0.f};

  for (int k0 = 0; k0 < K; k0 += 64) {
    __syncthreads();
    gll16(gA0, lA0); gll16(gA1, lA1);
    gll16(gB0, lB0); gll16(gB1, lB1); gll16(gB2, lB2); gll16(gB3, lB3);
    gA0 += 64; gA1 += 64; gB0 += 64; gB1 += 64; gB2 += 64; gB3 += 64;
    __syncthreads();

#pragma unroll
    for (int h = 0; h < 2; ++h) {
      const int off = h ? off1 : off0;
      bf16x8 af[2], bfr[4];
#pragma unroll
      for (int i = 0; i < 2; ++i) af[i]  = *(const bf16x8*)(rA[i] + off);
#pragma unroll
      for (int j = 0; j < 4; ++j) bfr[j] = *(const bf16x8*)(rB[j] + off);
#pragma unroll
      for (int i = 0; i < 2; ++i)
#pragma unroll
        for (int j = 0; j < 4; ++j)
          acc[i][j] = MFMA16(af[i], bfr[j], acc[i][j]);
    }
  }

#pragma unroll
  for (int i = 0; i < 2; ++i) {
    const long row0 = m0 + wr * 32 + i * 16 + quad * 4;
#pragma unroll
    for (int j = 0; j < 4; ++j) {
      const long col = n0 + wc * 64 + j * 16 + c16;
      const float bv = bias[col];
#pragma unroll
      for (int r = 0; r < 4; ++r)
        C[(row0 + r) * N + col] = acc[i][j][r] + bv;
    }
  }
}

// ---------------------------------------------------------------------------
// V repack: Vb(S,D) -> VTp(h, d, key+256) transposed; zeroes pad tiles of
// both Kp and VTp. Grid (72 padded key tiles, 16 heads), 256 threads.
// Dual-XOR swizzled LDS transpose -> both write and read conflict-free.
// ---------------------------------------------------------------------------
__global__ __launch_bounds__(256, 2) void repack_v(
    const u16* __restrict__ Vb, u16* __restrict__ Kp, u16* __restrict__ VTp)
{
  __shared__ u16 lds[64 * 64];
  const int tile = blockIdx.x;          // padded key tile, 0..71
  const int h    = blockIdx.y;
  const int tid  = threadIdx.x;
  const int kt   = tile * 64 - 256;     // actual key start
  const long vtb = (long)h * 64 * 4608;

  if (kt < 0 || kt >= 4096) {           // pad tile: zero Kp rows + VTp cols
    const int4 z = {0, 0, 0, 0};
    for (int idx = tid; idx < 512; idx += 256) {
      const int r = idx >> 3, c = idx & 7;
      *(int4*)(&Kp[((long)h * 4608 + tile * 64 + r) * 64 + c * 8]) = z;
      *(int4*)(&VTp[vtb + (long)r * 4608 + tile * 64 + c * 8])     = z;
    }
    return;
  }

  for (int idx = tid; idx < 512; idx += 256) {
    const int r = idx >> 3, c = idx & 7;            // key r, d-chunk c
    U8x16 t; t.v = *(const int4*)(&Vb[(long)(kt + r) * 1024 + h * 64 + c * 8]);
#pragma unroll
    for (int j = 0; j < 8; ++j) {
      const int d = c * 8 + j;
      lds[d * 64 + (((r >> 3) ^ ((c + j) & 7)) * 8) + (r & 7)] = t.u[j];
    }
  }
  __syncthreads();
  for (int idx = tid; idx < 512; idx += 256) {
    const int d = idx >> 3, c2 = idx & 7;           // d row, key-chunk c2
    const int sl = (c2 ^ ((d + (d >> 3)) & 7)) * 8;
    const int4 v = *(const int4*)(&lds[d * 64 + sl]);
    *(int4*)(&VTp[vtb + (long)d * 4608 + 256 + kt + c2 * 8]) = v;
  }
}

// ---------------------------------------------------------------------------
// Sliding-window flash attention. Grid (S/128, H) = 512 blocks, 256 thr =
// 4 waves. Wave w owns queries [qb0+32w, +32) (two 16-row subtiles).
// 10 key tiles of 64 cover padded keys [qb0, qb0+640); wave w computes the
// 9 tiles intersecting its band: t in [w>>1, 8+(w>>1)] (skip is wave-uniform,
// placed after both barriers).
// Fixed-max softmax (|s| <~ 8 << 88): p = exp(s/8); pad keys (k=0,v=0) give
// p=1 in denominator, matching reference zero-padding exactly.
// P per-wave in LDS (C-layout -> A-layout), slot-swizzled.
// ---------------------------------------------------------------------------
__global__ __launch_bounds__(256, 4) void swa_fused(
    const u16* __restrict__ Qb, const u16* __restrict__ Kp,
    const u16* __restrict__ VTp, u16* __restrict__ o)
{
  __shared__ u16 Ks[64 * 64];       // (key, d), slot-swizzled   8 KB
  __shared__ u16 Vs[64 * 64];       // (d, key), slot-swizzled   8 KB
  __shared__ u16 Ps[4 * 32 * 64];   // per-wave (q, key)        16 KB

  const int tid  = threadIdx.x;
  const int lane = tid & 63;
  const int w    = tid >> 6;
  const int quad = lane >> 4;
  const int c16  = lane & 15;
  const int h    = blockIdx.y;
  const int qb0  = blockIdx.x * 128;

  // Q fragments (A-layout) for both 16-row subtiles
  bf16x8 aq[2][2];
#pragma unroll
  for (int qa = 0; qa < 2; ++qa) {
    const long qrow = qb0 + w * 32 + qa * 16 + c16;
    aq[qa][0] = *(const bf16x8*)(&Qb[qrow * 1024 + h * 64 + quad * 8]);
    aq[qa][1] = *(const bf16x8*)(&Qb[qrow * 1024 + h * 64 + 32 + quad * 8]);
  }

  // staging: wave w covers rows [w*16, +16) of Ks (keys) and Vs (d)
  const int rowo   = lane >> 3;
  const int gchunk = (lane & 7) ^ rowo;
  const u16* gK0 = &Kp[((long)h * 4608 + qb0 + w * 16 + rowo) * 64 + gchunk * 8];
  const u16* gK1 = gK0 + 8 * 64;
  const u16* gV0 = &VTp[((long)h * 64 + w * 16 + rowo) * 4608 + qb0 + gchunk * 8];
  const u16* gV1 = gV0 + 8 * 4608;
  u16* const lK0 = &Ks[(w * 16) * 64];
  u16* const lK1 = lK0 + 8 * 64;
  u16* const lV0 = &Vs[(w * 16) * 64];
  u16* const lV1 = lV0 + 8 * 64;

  const int rsw  = c16 & 7;
  const int off0 = (quad ^ rsw) * 8;
  const int off1 = ((4 + quad) ^ rsw) * 8;
  const u16* rK[4]; const u16* rV[4];
#pragma unroll
  for (int i = 0; i < 4; ++i) {
    rK[i] = &Ks[(i * 16 + c16) * 64];
    rV[i] = &Vs[(i * 16 + c16) * 64];
  }
  u16* const Pw = &Ps[w * 2048];
  const u16* rP[2];
#pragma unroll
  for (int qa = 0; qa < 2; ++qa) rP[qa] = &Pw[(qa * 16 + c16) * 64];

  const int t_lo = w >> 1;            // waves 0,1: tiles 0..8; waves 2,3: 1..9
  const int t_hi = 8 + (w >> 1);
  int dbase[2];
#pragma unroll
  for (int qa = 0; qa < 2; ++qa)
    dbase[qa] = c16 - w * 32 - qa * 16 - quad * 4;

  f32x4 acc[2][4];
#pragma unroll
  for (int qa = 0; qa < 2; ++qa)
#pragma unroll
    for (int dt = 0; dt < 4; ++dt) acc[qa][dt] = f32x4{0.f, 0.f, 0.f, 0.f};
  float rsum[2][4] = {{0.f, 0.f, 0.f, 0.f}, {0.f, 0.f, 0.f, 0.f}};

  for (int t = 0; t < 10; ++t) {
    __syncthreads();
    gll16(gK0, lK0); gll16(gK1, lK1);
    gll16(gV0, lV0); gll16(gV1, lV1);
    gK0 += 64 * 64; gK1 += 64 * 64; gV0 += 64; gV1 += 64;
    __syncthreads();
    if (t < t_lo || t > t_hi) continue;

    // S = Q K^T ; mask+exp ; P -> LDS (per-wave)
#pragma unroll
    for (int tcol = 0; tcol < 4; ++tcol) {
      const bf16x8 bk0 = *(const bf16x8*)(rK[tcol] + off0);
      const bf16x8 bk1 = *(const bf16x8*)(rK[tcol] + off1);
#pragma unroll
      for (int qa = 0; qa < 2; ++qa) {
        f32x4 s = f32x4{0.f, 0.f, 0.f, 0.f};
        s = MFMA16(aq[qa][0], bk0, s);
        s = MFMA16(aq[qa][1], bk1, s);
#pragma unroll
        for (int r = 0; r < 4; ++r) {
          const int delta = dbase[qa] + t * 64 + tcol * 16 - r;
          const float p = ((u32)delta < 512u) ? __expf(s[r] * 0.125f) : 0.f;
          rsum[qa][r] += p;
          const int qi = qa * 16 + quad * 4 + r;
          const int kc = tcol * 16 + c16;
          Pw[qi * 64 + (((kc >> 3) ^ (qi & 7)) * 8) + (kc & 7)] = f2b(p);
        }
      }
    }

    // O += P V
#pragma unroll
    for (int qa = 0; qa < 2; ++qa) {
      const bf16x8 ap0 = *(const bf16x8*)(rP[qa] + off0);
      const bf16x8 ap1 = *(const bf16x8*)(rP[qa] + off1);
#pragma unroll
      for (int dt = 0; dt < 4; ++dt) {
        const bf16x8 bv0 = *(const bf16x8*)(rV[dt] + off0);
        const bf16x8 bv1 = *(const bf16x8*)(rV[dt] + off1);
        acc[qa][dt] = MFMA16(ap0, bv0, acc[qa][dt]);
        acc[qa][dt] = MFMA16(ap1, bv1, acc[qa][dt]);
      }
    }
  }

  // row-sum reduction across the 16 lanes holding each C-row
#pragma unroll
  for (int off = 1; off < 16; off <<= 1)
#pragma unroll
    for (int qa = 0; qa < 2; ++qa)
#pragma unroll
      for (int r = 0; r < 4; ++r)
        rsum[qa][r] += __shfl_xor(rsum[qa][r], off, 64);

#pragma unroll
  for (int qa = 0; qa < 2; ++qa) {
    const int qp = qb0 + w * 32 + qa * 16 + quad * 4;
#pragma unroll
    for (int r = 0; r < 4; ++r) {
      const float inv = 1.f / rsum[qa][r];
#pragma unroll
      for (int dt = 0; dt < 4; ++dt)
        o[(long)(qp + r) * 1024 + h * 64 + dt * 16 + c16] = f2b(acc[qa][dt][r] * inv);
    }
  }
}

// ---------------------------------------------------------------------------
extern "C" void kernel_launch(void* const* d_in, const int* in_sizes, int n_in,
                              void* d_out, int out_size, void* d_ws, size_t ws_size,
                              hipStream_t stream)
{
  const float* x    = (const float*)d_in[0];   // (4096, 1024)
  const float* Wqkv = (const float*)d_in[1];   // (3072, 1024)
  const float* bqkv = (const float*)d_in[2];   // (3072,)
  const float* Wout = (const float*)d_in[3];   // (1024, 1024)
  const float* bout = (const float*)d_in[4];   // (1024,)
  float* out = (float*)d_out;                  // (4096, 1024)

  // ws layout (u16 elements): 52.4 MB total
  u16* xb    = (u16*)d_ws;                         // 4096*1024
  u16* wqkvb = xb    + (size_t)4096 * 1024;        // 3072*1024
  u16* woutb = wqkvb + (size_t)3072 * 1024;        // 1024*1024
  u16* Qb    = woutb + (size_t)1024 * 1024;        // 4096*1024
  u16* Kp    = Qb    + (size_t)4096 * 1024;        // 16*4608*64
  u16* VTp   = Kp    + (size_t)16 * 4608 * 64;     // 16*64*4608
  u16* Vb    = VTp   + (size_t)16 * 4608 * 64;     // 4096*1024 (o aliases)
  u16* o     = Vb;                                 // Vb dead after repack_v

  cvt_f32_bf16<<<4096 * 1024 / 8 / 256, 256, 0, stream>>>(x, xb, 4096 * 1024 / 8);
  cvt_f32_bf16<<<3072 * 1024 / 8 / 256, 256, 0, stream>>>(Wqkv, wqkvb, 3072 * 1024 / 8);
  cvt_f32_bf16<<<1024 * 1024 / 8 / 256, 256, 0, stream>>>(Wout, woutb, 1024 * 1024 / 8);

  gemm_qkv<<<dim3(3072 / 128, 4096 / 128), 256, 0, stream>>>(
      xb, wqkvb, bqkv, Qb, Kp, Vb);
  repack_v<<<dim3(72, 16), 256, 0, stream>>>(Vb, Kp, VTp);
  swa_fused<<<dim3(4096 / 128, 16), 256, 0, stream>>>(Qb, Kp, VTp, o);
  gemm_out<<<dim3(1024 / 128, 4096 / 64), 256, 0, stream>>>(o, woutb, bout, out);
}